// Round 1
// baseline (330.350 us; speedup 1.0000x reference)
//
#include <hip/hip_runtime.h>

#define Bsz 32
#define Tsz 1024
#define Din 512
#define Hsz 512
#define Mtot (Bsz * Tsz)   // 32768
#define Ntot Hsz           // 512
#define Ktot Din           // 512

#define BM 128
#define BN 128
#define BK 16
#define LDSA (BM + 4)
#define LDSB (BN + 4)

// ---------------------------------------------------------------------------
// Phase 1: fp32 GEMM  C[m,n] = sum_k A[m,k]*B[k,n] + bias[n]
// A = inputs flattened [Mtot, Ktot], B = kernel [Ktot, Ntot]
// ---------------------------------------------------------------------------
__global__ __launch_bounds__(256) void sgemm_currents(
    const float* __restrict__ A, const float* __restrict__ B,
    const float* __restrict__ bias, float* __restrict__ C)
{
    __shared__ float As[BK][LDSA];   // transposed A tile: As[k][m]
    __shared__ float Bs[BK][LDSB];   // Bs[k][n]

    const int tid = threadIdx.x;
    const int tx  = tid & 15;        // output col group
    const int ty  = tid >> 4;        // output row group
    const int m0  = blockIdx.y * BM;
    const int n0  = blockIdx.x * BN;

    const int arow = tid >> 2;          // 0..63
    const int ac4  = (tid & 3) * 4;     // 0,4,8,12
    const int brow = tid >> 5;          // 0..7
    const int bc4  = (tid & 31) * 4;    // 0..124

    float acc[8][8];
#pragma unroll
    for (int i = 0; i < 8; ++i)
#pragma unroll
        for (int j = 0; j < 8; ++j) acc[i][j] = 0.f;

    const float* Abase = A + (size_t)(m0 + arow) * Ktot + ac4;
    const float* Bbase = B + (size_t)brow * Ntot + n0 + bc4;

    float4 a0 = *reinterpret_cast<const float4*>(Abase);
    float4 a1 = *reinterpret_cast<const float4*>(Abase + (size_t)64 * Ktot);
    float4 b0 = *reinterpret_cast<const float4*>(Bbase);
    float4 b1 = *reinterpret_cast<const float4*>(Bbase + (size_t)8 * Ntot);

    const int NKT = Ktot / BK;
    for (int kt = 0; kt < NKT; ++kt) {
        // write staged regs to LDS
        {
            const float* ap = reinterpret_cast<const float*>(&a0);
            const float* aq = reinterpret_cast<const float*>(&a1);
#pragma unroll
            for (int j = 0; j < 4; ++j) As[ac4 + j][arow] = ap[j];
#pragma unroll
            for (int j = 0; j < 4; ++j) As[ac4 + j][arow + 64] = aq[j];
            *reinterpret_cast<float4*>(&Bs[brow][bc4])     = b0;
            *reinterpret_cast<float4*>(&Bs[brow + 8][bc4]) = b1;
        }
        __syncthreads();
        if (kt + 1 < NKT) {  // prefetch next tile into regs, overlaps compute
            const float* An = Abase + (kt + 1) * BK;
            const float* Bn = Bbase + (size_t)(kt + 1) * BK * Ntot;
            a0 = *reinterpret_cast<const float4*>(An);
            a1 = *reinterpret_cast<const float4*>(An + (size_t)64 * Ktot);
            b0 = *reinterpret_cast<const float4*>(Bn);
            b1 = *reinterpret_cast<const float4*>(Bn + (size_t)8 * Ntot);
        }
#pragma unroll
        for (int k = 0; k < BK; ++k) {
            float4 af0 = *reinterpret_cast<const float4*>(&As[k][ty * 8]);
            float4 af1 = *reinterpret_cast<const float4*>(&As[k][ty * 8 + 4]);
            float4 bf0 = *reinterpret_cast<const float4*>(&Bs[k][tx * 8]);
            float4 bf1 = *reinterpret_cast<const float4*>(&Bs[k][tx * 8 + 4]);
            const float av[8] = {af0.x, af0.y, af0.z, af0.w,
                                 af1.x, af1.y, af1.z, af1.w};
            const float bv[8] = {bf0.x, bf0.y, bf0.z, bf0.w,
                                 bf1.x, bf1.y, bf1.z, bf1.w};
#pragma unroll
            for (int i = 0; i < 8; ++i)
#pragma unroll
                for (int j = 0; j < 8; ++j)
                    acc[i][j] = fmaf(av[i], bv[j], acc[i][j]);
        }
        __syncthreads();
    }

    const float4 bi0 = *reinterpret_cast<const float4*>(&bias[n0 + tx * 8]);
    const float4 bi1 = *reinterpret_cast<const float4*>(&bias[n0 + tx * 8 + 4]);
#pragma unroll
    for (int i = 0; i < 8; ++i) {
        const size_t row = (size_t)(m0 + ty * 8 + i);
        float4 o0 = make_float4(acc[i][0] + bi0.x, acc[i][1] + bi0.y,
                                acc[i][2] + bi0.z, acc[i][3] + bi0.w);
        float4 o1 = make_float4(acc[i][4] + bi1.x, acc[i][5] + bi1.y,
                                acc[i][6] + bi1.z, acc[i][7] + bi1.w);
        float* cp = C + row * Ntot + n0 + tx * 8;
        *reinterpret_cast<float4*>(cp)     = o0;
        *reinterpret_cast<float4*>(cp + 4) = o1;
    }
}

// ---------------------------------------------------------------------------
// Phase 2: sequential LIF scan over T. One thread per (b,h) sequence.
// Manual depth-8 load pipeline (register ring, static indices) so current
// loads stay ~8 iterations ahead of use even without __restrict__ (cur may
// alias the vmem output region in the fallback path).
// ---------------------------------------------------------------------------
__global__ __launch_bounds__(256) void lif_scan(
    const float* cur, float* spikes, float* vmem,
    float* vfinal, float* partials)
{
    constexpr float A_M  = 0.95122942450071400910f;   // exp(-1/20) in fp32
    constexpr float OM_M = 1.0f - A_M;
    constexpr float A_S  = 0.81873075307798182354f;   // exp(-1/5) in fp32

    const int tid = threadIdx.x;
    const int gid = blockIdx.x * 256 + tid;           // 0..16383
    const size_t base = ((size_t)(gid >> 9)) * (size_t)Tsz * Hsz + (gid & 511);

    float v = 0.f, isyn = 0.f, acc = 0.f;

    constexpr int P = 8;
    float ring[P];
#pragma unroll
    for (int p = 0; p < P; ++p) ring[p] = cur[base + (size_t)p * Hsz];

    for (int t = 0; t < Tsz; t += P) {
#pragma unroll
        for (int p = 0; p < P; ++p) {
            const float c = ring[p];
            // prefetch t+P+p (clamped; tail loads are dead but harmless,
            // and clamp keeps them at addresses not yet overwritten)
            int tn = t + P + p;
            tn = tn < (Tsz - 1) ? tn : (Tsz - 1);
            ring[p] = cur[base + (size_t)tn * Hsz];

            isyn = fmaf(A_S, isyn, c);
            v    = fmaf(A_M, v, OM_M * isyn);
            const float sp = (v >= 1.0f) ? 1.0f : 0.0f;
            const float x  = 4.0f * (v - 1.0f);
            const float ep = __expf(x);
            const float em = __expf(-x);
            // surrogate = beta / (2*(1+cosh(x))) = 4 / (2 + e^x + e^-x)
            const float surr = 4.0f / (2.0f + ep + em);
            const float so   = fmaf(2.0f, sp, -surr);  // 2*spike - surrogate
            v = (sp > 0.f) ? 0.0f : v;                 // reset

            const size_t idx = base + (size_t)(t + p) * Hsz;
            spikes[idx] = so;
            vmem[idx]   = v;
            acc += so;
        }
    }
    vfinal[gid] = v;

    // block-level reduction of spike sum (deterministic, no global atomics)
#pragma unroll
    for (int off = 32; off; off >>= 1) acc += __shfl_down(acc, off);
    __shared__ float wsum[4];
    if ((tid & 63) == 0) wsum[tid >> 6] = acc;
    __syncthreads();
    if (tid == 0)
        partials[blockIdx.x] = (wsum[0] + wsum[1]) + (wsum[2] + wsum[3]);
}

__global__ __launch_bounds__(64) void rate_finalize(
    const float* __restrict__ partials, float* __restrict__ rate)
{
    float s = partials[threadIdx.x];
#pragma unroll
    for (int off = 32; off; off >>= 1) s += __shfl_down(s, off);
    if (threadIdx.x == 0)
        rate[0] = s * (1.0f / 16777216.0f);   // / (B*T*H), exact 2^-24
}

// ---------------------------------------------------------------------------
extern "C" void kernel_launch(void* const* d_in, const int* in_sizes, int n_in,
                              void* d_out, int out_size, void* d_ws, size_t ws_size,
                              hipStream_t stream)
{
    const float* inputs = (const float*)d_in[0];   // [B,T,Din] fp32
    const float* weight = (const float*)d_in[1];   // [Din,H]   fp32
    const float* bias   = (const float*)d_in[2];   // [H]       fp32

    float* out    = (float*)d_out;
    float* spikes = out;                                  // [B,T,H]
    float* vmem   = out + (size_t)Bsz * Tsz * Hsz;        // [B,T,H]
    float* vfinal = out + 2 * (size_t)Bsz * Tsz * Hsz;    // [B,H]
    float* rate   = vfinal + (size_t)Bsz * Hsz;           // scalar

    float* partials = (float*)d_ws;                       // 64 floats
    const size_t CUR_BYTES = (size_t)Mtot * Ntot * sizeof(float);  // 64 MiB

    float* cur;
    if (ws_size >= CUR_BYTES + 1024)
        cur = (float*)((char*)d_ws + 1024);
    else
        cur = vmem;  // fallback: stage currents in the membrane output region
                     // (each element is read before the scan overwrites it)

    dim3 ggrid(Ntot / BN, Mtot / BM);   // (4, 256)
    sgemm_currents<<<ggrid, 256, 0, stream>>>(inputs, weight, bias, cur);
    lif_scan<<<dim3(64), 256, 0, stream>>>(cur, spikes, vmem, vfinal, partials);
    rate_finalize<<<dim3(1), 64, 0, stream>>>(partials, rate);
}